// Round 4
// baseline (70.674 us; speedup 1.0000x reference)
//
#include <hip/hip_runtime.h>

// SPH pressure-gradient segmented scatter-reduce. i is SORTED.
// R4: CHUNK=8 — amortize the fixed per-thread costs (64-lane segmented scan,
// segment bookkeeping) over twice the edges; 10x16B stream loads in flight
// per thread for latency hiding. Wave scan -> ~14 atomic pairs per 512 edges.

constexpr int CHUNK = 8;

__global__ void pack_pv(const float* __restrict__ p,
                        const float* __restrict__ V,
                        float2* __restrict__ pv, int N)
{
    int n = blockIdx.x * blockDim.x + threadIdx.x;
    if (n < N) pv[n] = make_float2(p[n], V[n]);
}

__global__ __launch_bounds__(256) void edge_kernel(
    const int*    __restrict__ ei,
    const int*    __restrict__ ej,
    const float*  __restrict__ dirs,   // [E*2] interleaved x,y
    const float*  __restrict__ qarr,
    const float*  __restrict__ support,
    const float*  __restrict__ p_i,
    const float2* __restrict__ pv,     // packed {p, V}
    float*        __restrict__ acc,    // [N*2], pre-zeroed
    long long E)
{
    long long t    = blockIdx.x * (long long)blockDim.x + threadIdx.x;
    long long base = t * CHUNK;
    const int lane = threadIdx.x & 63;

    int   cur = -1;
    float ax = 0.0f, ay = 0.0f;

    if (base < E) {
        const float h    = support[0];
        const float coef = -20.0f * (7.0f / 3.14159265358979323846f) / (h * h * h);

        int   ii[CHUNK], jj[CHUNK];
        float qq[CHUNK], dxv[CHUNK], dyv[CHUNK];
        int   nk;

        if (base + CHUNK <= E) {
            // coalesced vector loads: 2x int4 (i), 2x int4 (j), 2x float4 (q), 4x float4 (dirs)
            const int4*   pi4 = (const int4*)  (ei   + base);
            const int4*   pj4 = (const int4*)  (ej   + base);
            const float4* pq4 = (const float4*)(qarr + base);
            const float4* pd4 = (const float4*)(dirs + 2 * base);
            int4   ia = pi4[0], ib = pi4[1];
            int4   ja = pj4[0], jb = pj4[1];
            float4 qa = pq4[0], qb = pq4[1];
            float4 d0 = pd4[0], d1 = pd4[1], d2 = pd4[2], d3 = pd4[3];
            ii[0]=ia.x; ii[1]=ia.y; ii[2]=ia.z; ii[3]=ia.w;
            ii[4]=ib.x; ii[5]=ib.y; ii[6]=ib.z; ii[7]=ib.w;
            jj[0]=ja.x; jj[1]=ja.y; jj[2]=ja.z; jj[3]=ja.w;
            jj[4]=jb.x; jj[5]=jb.y; jj[6]=jb.z; jj[7]=jb.w;
            qq[0]=qa.x; qq[1]=qa.y; qq[2]=qa.z; qq[3]=qa.w;
            qq[4]=qb.x; qq[5]=qb.y; qq[6]=qb.z; qq[7]=qb.w;
            dxv[0]=d0.x; dyv[0]=d0.y; dxv[1]=d0.z; dyv[1]=d0.w;
            dxv[2]=d1.x; dyv[2]=d1.y; dxv[3]=d1.z; dyv[3]=d1.w;
            dxv[4]=d2.x; dyv[4]=d2.y; dxv[5]=d2.z; dyv[5]=d2.w;
            dxv[6]=d3.x; dyv[6]=d3.y; dxv[7]=d3.z; dyv[7]=d3.w;
            nk = CHUNK;
        } else {
            nk = (int)(E - base);
            #pragma unroll
            for (int k = 0; k < CHUNK; ++k) {
                if (k < nk) {
                    ii[k]  = ei[base + k];
                    jj[k]  = ej[base + k];
                    qq[k]  = qarr[base + k];
                    dxv[k] = dirs[2 * (base + k)];
                    dyv[k] = dirs[2 * (base + k) + 1];
                } else { ii[k] = 0; jj[k] = 0; qq[k] = 0.0f; dxv[k] = 0.0f; dyv[k] = 0.0f; }
            }
        }

        // gather phase: issue all scattered loads before dependent math (ILP)
        float2 pvv[CHUNK];
        float  piv[CHUNK];
        #pragma unroll
        for (int k = 0; k < CHUNK; ++k) pvv[k] = pv[jj[k]];
        #pragma unroll
        for (int k = 0; k < CHUNK; ++k) piv[k] = p_i[ii[k]];

        float w[CHUNK];
        #pragma unroll
        for (int k = 0; k < CHUNK; ++k) {
            float om = 1.0f - qq[k];
            w[k] = (piv[k] + pvv[k].x) * pvv[k].y * (coef * qq[k] * om * om * om);
        }

        // per-thread run-length accumulate; interior flush on segment change
        cur = ii[0];
        #pragma unroll
        for (int k = 0; k < CHUNK; ++k) {
            if (k < nk) {
                if (ii[k] != cur) {
                    atomicAdd(&acc[2 * cur],     ax);
                    atomicAdd(&acc[2 * cur + 1], ay);
                    cur = ii[k];
                    ax = 0.0f; ay = 0.0f;
                }
                ax += w[k] * dxv[k];
                ay += w[k] * dyv[k];
            }
        }
    }

    // wave-level segmented inclusive scan over (cur, ax, ay); keys sorted.
    #pragma unroll
    for (int d = 1; d < 64; d <<= 1) {
        int   oc  = __shfl_up(cur, d);
        float oax = __shfl_up(ax,  d);
        float oay = __shfl_up(ay,  d);
        if (lane >= d && oc == cur) { ax += oax; ay += oay; }
    }
    int nxt = __shfl_down(cur, 1);
    if (cur >= 0 && (lane == 63 || nxt != cur)) {
        atomicAdd(&acc[2 * cur],     ax);
        atomicAdd(&acc[2 * cur + 1], ay);
    }
}

__global__ void finalize_kernel(float2* __restrict__ out,
                                const float* __restrict__ rhoi,
                                int N)
{
    int n = blockIdx.x * blockDim.x + threadIdx.x;
    if (n < N) {
        float2 a  = out[n];
        float  sc = -1.0f / rhoi[n];
        out[n] = make_float2(a.x * sc, a.y * sc);
    }
}

extern "C" void kernel_launch(void* const* d_in, const int* in_sizes, int n_in,
                              void* d_out, int out_size, void* d_ws, size_t ws_size,
                              hipStream_t stream)
{
    // 0:i 1:j 2:ri 3:rj 4:Vi 5:Vj 6:distances 7:radialDistances
    // 8:support 9:numParticles 10:eps 11:rhoi 12:rhoj 13:pi 14:pj
    const int*   ei      = (const int*)  d_in[0];
    const int*   ej      = (const int*)  d_in[1];
    const float* Vj      = (const float*)d_in[5];
    const float* dirs    = (const float*)d_in[6];
    const float* qarr    = (const float*)d_in[7];
    const float* support = (const float*)d_in[8];
    const float* rhoi    = (const float*)d_in[11];
    const float* p_i     = (const float*)d_in[13];
    const float* p_j     = (const float*)d_in[14];

    const long long E = in_sizes[0];
    const int       N = in_sizes[11];

    float* out = (float*)d_out;
    hipMemsetAsync(out, 0, (size_t)N * 2 * sizeof(float), stream);

    const int block = 256;
    float2* pv = (float2*)d_ws;   // ws_size is ample for N*8 bytes
    pack_pv<<<(N + block - 1) / block, block, 0, stream>>>(p_j, Vj, pv, N);

    const long long nthreads = (E + CHUNK - 1) / CHUNK;
    const int grid = (int)((nthreads + block - 1) / block);
    edge_kernel<<<grid, block, 0, stream>>>(ei, ej, dirs, qarr, support,
                                            p_i, pv, out, E);

    finalize_kernel<<<(N + block - 1) / block, block, 0, stream>>>((float2*)out, rhoi, N);
}

// Round 5
// 65.999 us; speedup vs baseline: 1.0708x; 1.0708x over previous
//
#include <hip/hip_runtime.h>

// SPH pressure-gradient, CSR restructure. i is SORTED => edge list is CSR.
// R5: build offsets[] (one streaming boundary pass, fused with {p,V} pack),
// then one 16-lane group per particle: contiguous edge range, coalesced
// stream loads, 4-step shfl_xor group reduce, ONE plain store per particle.
// No atomics, no segmented scan, no memset, finalize fused.

constexpr int FC = 8;  // edges per thread in the offsets/boundary pass

// Fused prep: (a) threads t<N pack pv[t]={p[t],V[t]};
//             (b) each thread scans FC edges of ei for boundaries:
//                 offsets[n] = first e with ei[e] >= n;  offsets[N] = E.
__global__ __launch_bounds__(256) void prep_kernel(
    const int*   __restrict__ ei,
    const float* __restrict__ p,
    const float* __restrict__ V,
    int*         __restrict__ offsets,  // [N+1]
    float2*      __restrict__ pv,       // [N]
    long long E, int N)
{
    long long t = blockIdx.x * (long long)blockDim.x + threadIdx.x;

    if (t < N) pv[t] = make_float2(p[t], V[t]);

    long long base = t * FC;
    if (base >= E) return;

    int v[FC + 1];
    if (base + FC <= E) {
        const int4* p4 = (const int4*)(ei + base);
        int4 a = p4[0], b = p4[1];
        v[0]=a.x; v[1]=a.y; v[2]=a.z; v[3]=a.w;
        v[4]=b.x; v[5]=b.y; v[6]=b.z; v[7]=b.w;
        v[FC] = (base + FC < E) ? ei[base + FC] : N;
    } else {
        #pragma unroll
        for (int k = 0; k <= FC; ++k)
            v[k] = (base + k < E) ? (int)ei[base + k] : N;
    }

    if (base == 0) {
        for (int n = 0; n <= v[0]; ++n) offsets[n] = 0;
    }
    #pragma unroll
    for (int k = 0; k < FC; ++k) {
        int a = v[k], b = v[k + 1];
        for (int n = a + 1; n <= b; ++n) offsets[n] = (int)(base + k + 1);
    }
}

template <bool PACKED>
__global__ __launch_bounds__(256) void particle_kernel(
    const int*    __restrict__ offsets,  // [N+1]
    const int*    __restrict__ ej,
    const float*  __restrict__ dirs,     // [E*2] interleaved
    const float*  __restrict__ qarr,
    const float*  __restrict__ support,
    const float*  __restrict__ p_i,
    const float2* __restrict__ pv,       // packed {p,V}
    const float*  __restrict__ p_j,
    const float*  __restrict__ Vj,
    const float*  __restrict__ rhoi,
    float2*       __restrict__ out,      // [N]
    int N)
{
    int tid = blockIdx.x * blockDim.x + threadIdx.x;
    int n   = tid >> 4;          // particle = 16-lane group
    int sub = tid & 15;
    if (n >= N) return;

    const float h    = support[0];
    const float coef = -20.0f * (7.0f / 3.14159265358979323846f) / (h * h * h);

    int s = offsets[n];
    int e = offsets[n + 1];

    float pin = p_i[n];
    float ax = 0.0f, ay = 0.0f;

    for (int k = s + sub; k < e; k += 16) {
        int    jv = ej[k];
        float  q  = qarr[k];
        float2 d  = *(const float2*)(dirs + 2 * k);
        float pjv, vjv;
        if (PACKED) {
            float2 t2 = pv[jv];
            pjv = t2.x; vjv = t2.y;
        } else {
            pjv = p_j[jv];
            vjv = Vj[jv];
        }
        float om = 1.0f - q;
        float w  = (pin + pjv) * vjv * (coef * q * om * om * om);
        ax += w * d.x;
        ay += w * d.y;
    }

    // 4-step reduce within the 16-lane group (xor masks stay in-group)
    #pragma unroll
    for (int m = 8; m >= 1; m >>= 1) {
        ax += __shfl_xor(ax, m);
        ay += __shfl_xor(ay, m);
    }

    if (sub == 0) {
        float sc = -1.0f / rhoi[n];
        out[n] = make_float2(ax * sc, ay * sc);
    }
}

extern "C" void kernel_launch(void* const* d_in, const int* in_sizes, int n_in,
                              void* d_out, int out_size, void* d_ws, size_t ws_size,
                              hipStream_t stream)
{
    // 0:i 1:j 2:ri 3:rj 4:Vi 5:Vj 6:distances 7:radialDistances
    // 8:support 9:numParticles 10:eps 11:rhoi 12:rhoj 13:pi 14:pj
    const int*   ei      = (const int*)  d_in[0];
    const int*   ej      = (const int*)  d_in[1];
    const float* Vj      = (const float*)d_in[5];
    const float* dirs    = (const float*)d_in[6];
    const float* qarr    = (const float*)d_in[7];
    const float* support = (const float*)d_in[8];
    const float* rhoi    = (const float*)d_in[11];
    const float* p_i     = (const float*)d_in[13];
    const float* p_j     = (const float*)d_in[14];

    const long long E = in_sizes[0];
    const int       N = in_sizes[11];

    // workspace layout: offsets[N+1] ints, then pv[N] float2 (16B aligned)
    size_t off_bytes = ((size_t)(N + 1) * sizeof(int) + 15) & ~(size_t)15;
    int*    offsets = (int*)d_ws;
    float2* pv      = (float2*)((char*)d_ws + off_bytes);
    const bool packed = (ws_size >= off_bytes + (size_t)N * sizeof(float2));

    const int block = 256;

    long long prep_threads = (E + FC - 1) / FC;
    if (prep_threads < N) prep_threads = N;
    int prep_grid = (int)((prep_threads + block - 1) / block);
    prep_kernel<<<prep_grid, block, 0, stream>>>(ei, p_j, Vj, offsets, pv, E, N);

    long long main_threads = (long long)N * 16;
    int main_grid = (int)((main_threads + block - 1) / block);
    if (packed) {
        particle_kernel<true ><<<main_grid, block, 0, stream>>>(
            offsets, ej, dirs, qarr, support, p_i, pv, p_j, Vj, rhoi,
            (float2*)d_out, N);
    } else {
        particle_kernel<false><<<main_grid, block, 0, stream>>>(
            offsets, ej, dirs, qarr, support, p_i, pv, p_j, Vj, rhoi,
            (float2*)d_out, N);
    }
}